// Round 12
// baseline (628.794 us; speedup 1.0000x reference)
//
#include <hip/hip_runtime.h>

#define N_NODES 100000
#define N_EDGES 3200000
#define BATCH 16
#define BKT_SHIFT 6
#define BKT_NODES 64
#define K_BUCKETS 1563                 // ceil(100000/64)
#define NB 512                         // subchunks (E/NB = 6250 exact)
#define SUB (N_EDGES / NB)             // 6250
#define FT 512                         // build threads per block
#define CAP 4096                       // nodesort LDS capacity (bucket avg 2047, sigma 45)
#define DONE_CTR 1600                  // arrive counter (in totals[])
#define FLAG_CTR 1601                  // bptr-ready flag (in totals[])
#define PULL_CTR 1700                  // mega_pull barrier counter (in totals[])
#define PGRID 1563                     // ceil(N_NODES*4/256); <= 2048 co-resident

typedef float v4f __attribute__((ext_vector_type(4)));

// LEDGER (hard-won, do not retry):
//  - R3/R5: __builtin_nontemporal on gfx950 bypasses LLC too -> never NT here.
//  - R7: cooperative grid.sync() ~140us each on MI355X -> never.
//  - R8: per-block device-scope __threadfence() ~1us serialized (L2 wb) ->
//    cross-block handoff must be atomics-only (or sc1 data stores).
//  - R9/R10/R11: atomicExch publish + return-consume + atomicAdd(p,0) read-back
//    validated ~free; arrival-order cursors validated; resident-spin among
//    exactly-co-resident blocks validated (R11 build).
//  - R0-R5: pull = random 64-B line requests at ~3 TB/s fabric ceiling;
//    ~43us/layer is the gather floor. Launch gap ~11us/dispatch.

// ---- init: zero totals (incl. counters) and cursors. 1 block. ----
__global__ void zero_kernel(int* __restrict__ totals, int* __restrict__ cursor) {
    int t = threadIdx.x;
    for (int k = t; k < 2048; k += 256) totals[k] = 0;
    for (int k = t; k < K_BUCKETS; k += 256) cursor[k] = 0;
}

// ---- fused build: hist + totals + scan + LDS counting sort + copy-out in
// ONE dispatch (R11-validated). Grid = 512 = exactly 2 blocks/CU co-resident.
__global__ void __launch_bounds__(FT, 4) build_kernel(
        const int* __restrict__ row, const int* __restrict__ col,
        const float* __restrict__ w,
        int* __restrict__ totals, int* __restrict__ bptr,
        int* __restrict__ row_ptr, int* __restrict__ cursor,
        uint2* __restrict__ entries) {
    __shared__ uint2 sbuf[SUB];          // 50000 B
    __shared__ int lbeg[K_BUCKETS];      // 6252 B
    __shared__ int lcur[K_BUCKETS];      // 6252 B
    __shared__ int cross[FT / 64];       // 32 B
    __shared__ int crossg[FT / 64];      // 32 B
    __shared__ int lastflag;             //  4 B   (total 62572 B -> 2 blk/CU)
    int t = threadIdx.x, blk = blockIdx.x;
    int lane = t & 63, wv = t >> 6;
    int base = blk * SUB;

    // P1: histogram this subchunk into lcur
    for (int k = t; k < K_BUCKETS; k += FT) lcur[k] = 0;
    __syncthreads();
    for (int e = base + t; e < base + SUB; e += FT)
        atomicAdd(&lcur[row[e] >> BKT_SHIFT], 1);
    __syncthreads();

    // P2: publish per-bucket counts (return-consume), then arrive
    {
        int sink = 0;
        for (int k = t; k < K_BUCKETS; k += FT) {
            int v = lcur[k];
            if (v) sink += atomicAdd(&totals[k], v);
        }
        asm volatile("" :: "v"(sink));
    }
    __syncthreads();
    if (t == 0) {
        int old = atomicAdd(&totals[DONE_CTR], 1);
        lastflag = (old == (int)gridDim.x - 1);
    }
    __syncthreads();

    // P3: last arriver scans the 1563 totals -> bptr, sets flag
    if (lastflag) {
        int gloc[4];
        int gsum = 0;
        #pragma unroll
        for (int i = 0; i < 4; i++) {
            int idx = t * 4 + i;
            int v = (idx < K_BUCKETS) ? atomicAdd(&totals[idx], 0) : 0;
            gloc[i] = v;
            gsum += v;
        }
        int gpref = gsum;
        #pragma unroll
        for (int off = 1; off < 64; off <<= 1) {
            int u = __shfl_up(gpref, off, 64);
            if (lane >= off) gpref += u;
        }
        if (lane == 63) crossg[wv] = gpref;
        __syncthreads();
        int gwbase = 0;
        for (int i = 0; i < wv; i++) gwbase += crossg[i];
        int gexcl = gwbase + gpref - gsum;
        int sink = 0;
        #pragma unroll
        for (int i = 0; i < 4; i++) {
            int idx = t * 4 + i;
            if (idx < K_BUCKETS) sink += atomicExch(&bptr[idx], gexcl);
            gexcl += gloc[i];
        }
        asm volatile("" :: "v"(sink));
        __syncthreads();
        if (t == 0) {
            bptr[K_BUCKETS] = N_EDGES;
            row_ptr[N_NODES] = N_EDGES;
            int o = atomicExch(&totals[FLAG_CTR], 1);
            asm volatile("" :: "v"(o));
        }
    }

    // P4: block exclusive scan of lcur (wave-shuffle) -> cursors
    {
        int loc[4];
        int sum = 0;
        #pragma unroll
        for (int j = 0; j < 4; j++) {
            int k = t * 4 + j;
            int v = (k < K_BUCKETS) ? lcur[k] : 0;
            loc[j] = v;
            sum += v;
        }
        int pref = sum;
        #pragma unroll
        for (int off = 1; off < 64; off <<= 1) {
            int u = __shfl_up(pref, off, 64);
            if (lane >= off) pref += u;
        }
        if (lane == 63) cross[wv] = pref;
        __syncthreads();
        int wbase = 0;
        for (int i = 0; i < wv; i++) wbase += cross[i];
        int excl = wbase + pref - sum;
        #pragma unroll
        for (int j = 0; j < 4; j++) {
            int k = t * 4 + j;
            if (k < K_BUCKETS) { lbeg[k] = excl; lcur[k] = excl; }
            excl += loc[j];
        }
    }
    __syncthreads();

    // P5: scatter records into LDS (bucket-sorted)
    for (int e = base + t; e < base + SUB; e += FT) {
        int r = row[e];
        int bkt = r >> BKT_SHIFT;
        int pos = atomicAdd(&lcur[bkt], 1);
        sbuf[pos] = make_uint2(((unsigned)(r & (BKT_NODES - 1)) << 17) | (unsigned)col[e],
                               __float_as_uint(w[e]));
    }
    __syncthreads();

    // P6: wait for bptr (scanner set flag while we sorted)
    if (!lastflag) {
        if (t == 0)
            while (atomicAdd(&totals[FLAG_CTR], 0) == 0)
                __builtin_amdgcn_s_sleep(8);
        __syncthreads();
    }

    // P7: copy-out; slice base = bptr (atomic read) + arrival-order cursor
    int lane4 = t & 3;
    int sgbase = lane & ~3;
    for (int k = (t >> 2); k < K_BUCKETS; k += FT / 4) {
        int lb = lbeg[k];
        int le = lcur[k];
        int cnt = le - lb;
        int d0 = 0;
        if (lane4 == 0 && cnt > 0)
            d0 = atomicAdd(&bptr[k], 0) + atomicAdd(&cursor[k], cnt);
        d0 = __shfl(d0, sgbase, 64);
        for (int i = lb + lane4; i < le; i += 4)
            entries[d0 + (i - lb)] = sbuf[i];
    }
}

// ---- nodesort + layer 1 fused (unchanged, R6-validated) ----
__global__ void __launch_bounds__(256) nodesort_pull1_kernel(
        const int* __restrict__ bptr, uint2* __restrict__ entries,
        int* __restrict__ row_ptr,
        const float* __restrict__ x, float* __restrict__ out) {
    __shared__ uint2 ebuf[CAP];          // 32 KB
    __shared__ int nh[BKT_NODES];
    __shared__ int nc[BKT_NODES];
    __shared__ int nstart[BKT_NODES + 1];
    int t = threadIdx.x, b = blockIdx.x;
    int beg = bptr[b], end = bptr[b + 1];
    int n = min(end - beg, CAP);
    if (t < BKT_NODES) nh[t] = 0;
    __syncthreads();
    uint2 rs[16];
    int cnt = 0;
    #pragma unroll
    for (int i = 0; i < 16; i++) {
        int k = t + i * 256;
        if (k < n) {
            uint2 r = entries[beg + k];
            rs[i] = r;
            atomicAdd(&nh[r.x >> 17], 1);
            cnt = i + 1;
        }
    }
    __syncthreads();
    if (t < BKT_NODES) {
        int v = nh[t];
        int pref = v;
        #pragma unroll
        for (int off = 1; off < BKT_NODES; off <<= 1) {
            int u = __shfl_up(pref, off, 64);
            if (t >= off) pref += u;
        }
        int excl = pref - v;
        nstart[t] = excl;
        nc[t] = excl;
        if (t == BKT_NODES - 1) nstart[BKT_NODES] = pref;
        int node = b * BKT_NODES + t;
        if (node < N_NODES) row_ptr[node] = beg + excl;
    }
    __syncthreads();
    #pragma unroll
    for (int i = 0; i < 16; i++) {
        if (i < cnt) {
            uint2 r = rs[i];
            int pos = atomicAdd(&nc[r.x >> 17], 1);
            ebuf[pos] = r;
            entries[beg + pos] = r;
        }
    }
    __syncthreads();
    int ln = t >> 2, q = t & 3;
    int node = b * BKT_NODES + ln;
    if (node >= N_NODES) return;
    int s = nstart[ln], e = nstart[ln + 1];
    float4 acc = make_float4(0.f, 0.f, 0.f, 0.f);
    int i = s;
    while (i + 8 <= e) {
        uint2 r0 = ebuf[i + 0], r1 = ebuf[i + 1], r2 = ebuf[i + 2], r3 = ebuf[i + 3];
        uint2 r4 = ebuf[i + 4], r5 = ebuf[i + 5], r6 = ebuf[i + 6], r7 = ebuf[i + 7];
        float4 y0 = *(const float4*)&x[(r0.x & 0x1FFFFu) * BATCH + q * 4];
        float4 y1 = *(const float4*)&x[(r1.x & 0x1FFFFu) * BATCH + q * 4];
        float4 y2 = *(const float4*)&x[(r2.x & 0x1FFFFu) * BATCH + q * 4];
        float4 y3 = *(const float4*)&x[(r3.x & 0x1FFFFu) * BATCH + q * 4];
        float4 y4 = *(const float4*)&x[(r4.x & 0x1FFFFu) * BATCH + q * 4];
        float4 y5 = *(const float4*)&x[(r5.x & 0x1FFFFu) * BATCH + q * 4];
        float4 y6 = *(const float4*)&x[(r6.x & 0x1FFFFu) * BATCH + q * 4];
        float4 y7 = *(const float4*)&x[(r7.x & 0x1FFFFu) * BATCH + q * 4];
        float w0 = __uint_as_float(r0.y), w1 = __uint_as_float(r1.y);
        float w2 = __uint_as_float(r2.y), w3 = __uint_as_float(r3.y);
        float w4 = __uint_as_float(r4.y), w5 = __uint_as_float(r5.y);
        float w6 = __uint_as_float(r6.y), w7 = __uint_as_float(r7.y);
        acc.x += w0 * y0.x; acc.y += w0 * y0.y; acc.z += w0 * y0.z; acc.w += w0 * y0.w;
        acc.x += w1 * y1.x; acc.y += w1 * y1.y; acc.z += w1 * y1.z; acc.w += w1 * y1.w;
        acc.x += w2 * y2.x; acc.y += w2 * y2.y; acc.z += w2 * y2.z; acc.w += w2 * y2.w;
        acc.x += w3 * y3.x; acc.y += w3 * y3.y; acc.z += w3 * y3.z; acc.w += w3 * y3.w;
        acc.x += w4 * y4.x; acc.y += w4 * y4.y; acc.z += w4 * y4.z; acc.w += w4 * y4.w;
        acc.x += w5 * y5.x; acc.y += w5 * y5.y; acc.z += w5 * y5.z; acc.w += w5 * y5.w;
        acc.x += w6 * y6.x; acc.y += w6 * y6.y; acc.z += w6 * y6.z; acc.w += w6 * y6.w;
        acc.x += w7 * y7.x; acc.y += w7 * y7.y; acc.z += w7 * y7.z; acc.w += w7 * y7.w;
        i += 8;
    }
    for (; i < e; i++) {
        uint2 r = ebuf[i];
        float4 yv = *(const float4*)&x[(r.x & 0x1FFFFu) * BATCH + q * 4];
        float wj = __uint_as_float(r.y);
        acc.x += wj * yv.x; acc.y += wj * yv.y;
        acc.z += wj * yv.z; acc.w += wj * yv.w;
    }
    *(float4*)&out[node * BATCH + q * 4] = acc;
}

// ---- shared pull core: serial segment walk, identical accumulation order ----
__device__ __forceinline__ float4 pull_row(const float* __restrict__ y,
        const uint2* __restrict__ entries, int beg, int end, int q) {
    float4 acc = make_float4(0.f, 0.f, 0.f, 0.f);
    if (beg < end) {
        int lim = end - 1;
        uint2 r[8];
        #pragma unroll
        for (int j = 0; j < 8; j++) r[j] = entries[min(beg + j, lim)];
        int i = beg;
        while (i + 8 <= end) {
            float4 yv[8];
            #pragma unroll
            for (int j = 0; j < 8; j++)
                yv[j] = *(const float4*)&y[(r[j].x & 0x1FFFFu) * BATCH + q * 4];
            uint2 nx[8];
            #pragma unroll
            for (int j = 0; j < 8; j++)
                nx[j] = entries[min(i + 8 + j, lim)];
            #pragma unroll
            for (int j = 0; j < 8; j++) {
                float wj = __uint_as_float(r[j].y);
                acc.x += wj * yv[j].x;
                acc.y += wj * yv[j].y;
                acc.z += wj * yv[j].z;
                acc.w += wj * yv[j].w;
            }
            #pragma unroll
            for (int j = 0; j < 8; j++) r[j] = nx[j];
            i += 8;
        }
        if (i < end) {
            float4 yv[8];
            #pragma unroll
            for (int j = 0; j < 8; j++)
                yv[j] = *(const float4*)&y[(r[j].x & 0x1FFFFu) * BATCH + q * 4];
            #pragma unroll
            for (int j = 0; j < 8; j++)
                if (i + j < end) {
                    float wj = __uint_as_float(r[j].y);
                    acc.x += wj * yv[j].x;
                    acc.y += wj * yv[j].y;
                    acc.z += wj * yv[j].z;
                    acc.w += wj * yv[j].w;
                }
        }
    }
    return acc;
}

// ---- fallback single-layer pull (used when ws too small for buf2) ----
__global__ void __launch_bounds__(256) pull_kernel(const float* __restrict__ y,
                            const uint2* __restrict__ entries,
                            const int* __restrict__ row_ptr,
                            float* __restrict__ out) {
    int tid = blockIdx.x * blockDim.x + threadIdx.x;
    int node = tid >> 2;
    int q = tid & 3;
    if (node >= N_NODES) return;
    float4 acc = pull_row(y, entries, row_ptr[node], row_ptr[node + 1], q);
    *(float4*)&out[node * BATCH + q * 4] = acc;
}

// ---- device-scope visible store (write-through to the coherent point, the
// same coherence level our validated cross-block atomics use). NOT nt (R3/R5:
// nt skips the LLC; sc1 allocates there).
__device__ __forceinline__ void store_sc1(float* dst, float4 a) {
    v4f av = {a.x, a.y, a.z, a.w};
    asm volatile("global_store_dwordx4 %0, %1, off sc0 sc1"
                 :: "v"(dst), "v"(av) : "memory");
}

// ---- resident-spin grid barrier (R11-validated pattern): drain own stores,
// arrive, t0 spins with s_sleep. Safe: PGRID=1563 <= 2048 co-resident
// (no LDS, VGPR capped 64 by launch_bounds(256,8) -> 8 blocks/CU).
__device__ __forceinline__ void gbar(int* ctr, int target) {
    asm volatile("s_waitcnt vmcnt(0)" ::: "memory");
    __syncthreads();
    if (threadIdx.x == 0) {
        int o = atomicAdd(ctr, 1);
        asm volatile("" :: "v"(o));
        while (atomicAdd(ctr, 0) < target)
            __builtin_amdgcn_s_sleep(2);
    }
    __syncthreads();
}

// ---- layers 2-4 fused: persistent blocks, 2 in-kernel barriers.
// THREE-buffer rotation (yin -> mid1 -> mid2 -> mid1): every buffer is READ
// in exactly one layer, so no L1/L2 line is ever re-read stale. Inter-layer
// visibility: sc1 stores reach the coherent point before the barrier.
__global__ void __launch_bounds__(256, 8) mega_pull_kernel(
        const float* __restrict__ yin,   // buf   (written by nodesort_pull1)
        float* __restrict__ mid1,        // d_out (L2 out, L3 in, L4 out)
        float* __restrict__ mid2,        // buf2  (L3 out, L4 in)
        const uint2* __restrict__ entries,
        const int* __restrict__ row_ptr,
        int* __restrict__ ctr) {
    int tid = blockIdx.x * blockDim.x + threadIdx.x;
    int node = tid >> 2, q = tid & 3;
    bool act = node < N_NODES;
    int beg = 0, end = 0;
    if (act) { beg = row_ptr[node]; end = row_ptr[node + 1]; }
    // layer 2: yin -> mid1 (sc1)
    if (act) store_sc1(&mid1[node * BATCH + q * 4],
                       pull_row(yin, entries, beg, end, q));
    gbar(ctr, PGRID);
    // layer 3: mid1 -> mid2 (sc1)
    if (act) store_sc1(&mid2[node * BATCH + q * 4],
                       pull_row(mid1, entries, beg, end, q));
    gbar(ctr, 2 * PGRID);
    // layer 4: mid2 -> mid1 (= d_out); plain store, kernel-end flush
    if (act) {
        float4 a = pull_row(mid2, entries, beg, end, q);
        *(float4*)&mid1[node * BATCH + q * 4] = a;
    }
}

extern "C" void kernel_launch(void* const* d_in, const int* in_sizes, int n_in,
                              void* d_out, int out_size, void* d_ws, size_t ws_size,
                              hipStream_t stream) {
    const float* x   = (const float*)d_in[0];
    const float* w   = (const float*)d_in[1];
    const int*   row = (const int*)d_in[2];
    const int*   col = (const int*)d_in[3];
    float*       out = (float*)d_out;

    // ---- workspace carve-up: legacy prefix (32.43 MB, proven) + optional
    // buf2 at the tail (mega path only, guarded by ws_size) ----
    char* p = (char*)d_ws;
    uint2* entries = (uint2*)p;  p += (size_t)N_EDGES * sizeof(uint2);           // 25.6 MB
    float* buf     = (float*)p;  p += (size_t)N_NODES * BATCH * sizeof(float);   // 6.4 MB
    int* totals  = (int*)p;      p += 8192;
    int* bptr    = (int*)p;      p += 8192;
    int* cursor  = (int*)p;      p += 8192;
    int* row_ptr = (int*)p;      p += 400016;                                    // (N+1)*4 padded
    float* buf2  = (float*)p;
    size_t need = (size_t)((char*)buf2 - (char*)d_ws) + (size_t)N_NODES * BATCH * sizeof(float);

    // ---- build CSR: zero + fused build (R11) ----
    zero_kernel<<<1, 256, 0, stream>>>(totals, cursor);
    build_kernel<<<NB, FT, 0, stream>>>(row, col, w, totals, bptr, row_ptr,
                                        cursor, entries);

    // ---- nodesort + layer 1 fused (x -> buf) ----
    nodesort_pull1_kernel<<<K_BUCKETS, 256, 0, stream>>>(bptr, entries, row_ptr, x, buf);

    // ---- layers 2-4 ----
    if (ws_size >= need) {
        mega_pull_kernel<<<PGRID, 256, 0, stream>>>(buf, out, buf2, entries,
                                                    row_ptr, &totals[PULL_CTR]);
    } else {
        pull_kernel<<<PGRID, 256, 0, stream>>>(buf, entries, row_ptr, out);
        pull_kernel<<<PGRID, 256, 0, stream>>>(out, entries, row_ptr, buf);
        pull_kernel<<<PGRID, 256, 0, stream>>>(buf, entries, row_ptr, out);
    }
}

// Round 13
// 303.050 us; speedup vs baseline: 2.0749x; 2.0749x over previous
//
#include <hip/hip_runtime.h>

#define N_NODES 100000
#define N_EDGES 3200000
#define BATCH 16
#define BKT_SHIFT 6
#define BKT_NODES 64
#define K_BUCKETS 1563                 // ceil(100000/64)
#define NB 512                         // subchunks (E/NB = 6250 exact)
#define SUB (N_EDGES / NB)             // 6250
#define FT 512                         // build threads per block
#define CAP 4096                       // nodesort LDS capacity (bucket avg 2047, sigma 45)
#define DONE_CTR 1600                  // arrive counter (in totals[])
#define FLAG_CTR 1601                  // bptr-ready flag (in totals[])
#define INIT_CTR 2047                  // init-done flag (in totals[])
#define INIT_MAGIC 0x13579BDF          // implausible as harness poison

// LEDGER (hard-won, do not retry):
//  - R3/R5: __builtin_nontemporal on gfx950 bypasses LLC too -> never NT here.
//  - R7: cooperative grid.sync() ~140us each on MI355X -> never.
//  - R8: per-block device-scope __threadfence() ~1us serialized (L2 wb) ->
//    cross-block handoff must be atomics-only.
//  - R9/R10/R11: atomicExch publish + return-consume + atomicAdd(p,0) read-back
//    validated ~free; arrival-order cursors validated; resident-spin among
//    co-resident blocks validated for ONE-SHOT flags (R11 build).
//  - R12: grid-wide spin barrier with 1563 spinners DURING bulk traffic +
//    sc1 data stores = ~3x per-layer cost. The 3 pull dispatches are minimal.
//  - R0-R5: pull = random 64-B line requests at ~3 TB/s fabric ceiling;
//    ~43us/layer is the gather floor. Launch gap ~11us/dispatch.
//  - Cross-XCD: plain stores before an atomic flag are NOT visible (dirty
//    L2); zeroing shared atomics state must itself use atomics (Exch).

// ---- fused build: init + hist + totals + scan + LDS counting sort +
// copy-out in ONE dispatch. Grid = 512 = exactly 2 blocks/CU co-resident
// (62.6 KB LDS, VGPR<=128). Block 0 atomicExch-zeroes the shared atomic
// state and publishes INIT_MAGIC; others histogram first (~10us) then poll
// once. record: x = (r_local<<17)|col (col<2^17), y = w bits.
__global__ void __launch_bounds__(FT, 4) build_kernel(
        const int* __restrict__ row, const int* __restrict__ col,
        const float* __restrict__ w,
        int* __restrict__ totals, int* __restrict__ bptr,
        int* __restrict__ row_ptr, int* __restrict__ cursor,
        uint2* __restrict__ entries) {
    __shared__ uint2 sbuf[SUB];          // 50000 B
    __shared__ int lbeg[K_BUCKETS];      // 6252 B
    __shared__ int lcur[K_BUCKETS];      // 6252 B
    __shared__ int cross[FT / 64];       // 32 B
    __shared__ int crossg[FT / 64];      // 32 B
    __shared__ int lastflag;             //  4 B   (total 62572 B -> 2 blk/CU)
    int t = threadIdx.x, blk = blockIdx.x;
    int lane = t & 63, wv = t >> 6;
    int base = blk * SUB;

    // ---- P0 (block 0 only): atomicExch-zero shared atomic state, publish
    // init flag. Exch (not plain stores): zeroes must land at the coherent
    // point, else other XCDs' atomicAdds RMW stale lines (ledger).
    if (blk == 0) {
        int sink = 0;
        for (int k = t; k < INIT_CTR; k += FT) sink += atomicExch(&totals[k], 0);
        for (int k = t; k < K_BUCKETS; k += FT) sink += atomicExch(&cursor[k], 0);
        asm volatile("" :: "v"(sink));    // zeroes performed before flag
        __syncthreads();
        if (t == 0) {
            int o = atomicExch(&totals[INIT_CTR], INIT_MAGIC);
            asm volatile("" :: "v"(o));
        }
    }

    // ---- P1: histogram this subchunk into lcur (overlaps block 0's init) ----
    for (int k = t; k < K_BUCKETS; k += FT) lcur[k] = 0;
    __syncthreads();
    for (int e = base + t; e < base + SUB; e += FT)
        atomicAdd(&lcur[row[e] >> BKT_SHIFT], 1);
    __syncthreads();

    // ---- P1.5: wait for init (by now long done; ~single poll) ----
    if (blk != 0) {
        if (t == 0)
            while (atomicAdd(&totals[INIT_CTR], 0) != INIT_MAGIC)
                __builtin_amdgcn_s_sleep(2);
        __syncthreads();
    }

    // ---- P2: publish per-bucket counts (return-consume), then arrive ----
    {
        int sink = 0;
        for (int k = t; k < K_BUCKETS; k += FT) {
            int v = lcur[k];
            if (v) sink += atomicAdd(&totals[k], v);
        }
        asm volatile("" :: "v"(sink));
    }
    __syncthreads();
    if (t == 0) {
        int old = atomicAdd(&totals[DONE_CTR], 1);
        lastflag = (old == (int)gridDim.x - 1);
    }
    __syncthreads();

    // ---- P3: last arriver scans the 1563 totals -> bptr, sets flag ----
    if (lastflag) {
        int gloc[4];
        int gsum = 0;
        #pragma unroll
        for (int i = 0; i < 4; i++) {
            int idx = t * 4 + i;
            int v = (idx < K_BUCKETS) ? atomicAdd(&totals[idx], 0) : 0;
            gloc[i] = v;
            gsum += v;
        }
        int gpref = gsum;
        #pragma unroll
        for (int off = 1; off < 64; off <<= 1) {
            int u = __shfl_up(gpref, off, 64);
            if (lane >= off) gpref += u;
        }
        if (lane == 63) crossg[wv] = gpref;
        __syncthreads();
        int gwbase = 0;
        for (int i = 0; i < wv; i++) gwbase += crossg[i];
        int gexcl = gwbase + gpref - gsum;
        int sink = 0;
        #pragma unroll
        for (int i = 0; i < 4; i++) {
            int idx = t * 4 + i;
            if (idx < K_BUCKETS) sink += atomicExch(&bptr[idx], gexcl);
            gexcl += gloc[i];
        }
        asm volatile("" :: "v"(sink));    // publishes performed before flag
        __syncthreads();
        if (t == 0) {
            bptr[K_BUCKETS] = N_EDGES;    // consumed next kernel (coherent)
            row_ptr[N_NODES] = N_EDGES;
            int o = atomicExch(&totals[FLAG_CTR], 1);
            asm volatile("" :: "v"(o));
        }
    }

    // ---- P4: block exclusive scan of lcur (wave-shuffle) -> cursors ----
    {
        int loc[4];
        int sum = 0;
        #pragma unroll
        for (int j = 0; j < 4; j++) {
            int k = t * 4 + j;
            int v = (k < K_BUCKETS) ? lcur[k] : 0;
            loc[j] = v;
            sum += v;
        }
        int pref = sum;
        #pragma unroll
        for (int off = 1; off < 64; off <<= 1) {
            int u = __shfl_up(pref, off, 64);
            if (lane >= off) pref += u;
        }
        if (lane == 63) cross[wv] = pref;
        __syncthreads();
        int wbase = 0;
        for (int i = 0; i < wv; i++) wbase += cross[i];
        int excl = wbase + pref - sum;
        #pragma unroll
        for (int j = 0; j < 4; j++) {
            int k = t * 4 + j;
            if (k < K_BUCKETS) { lbeg[k] = excl; lcur[k] = excl; }
            excl += loc[j];
        }
    }
    __syncthreads();

    // ---- P5: scatter records into LDS (bucket-sorted); row re-read L2-hot ----
    for (int e = base + t; e < base + SUB; e += FT) {
        int r = row[e];
        int bkt = r >> BKT_SHIFT;
        int pos = atomicAdd(&lcur[bkt], 1);
        sbuf[pos] = make_uint2(((unsigned)(r & (BKT_NODES - 1)) << 17) | (unsigned)col[e],
                               __float_as_uint(w[e]));
    }
    __syncthreads();

    // ---- P6: wait for bptr (scanner set flag while we sorted) ----
    if (!lastflag) {
        if (t == 0)
            while (atomicAdd(&totals[FLAG_CTR], 0) == 0)
                __builtin_amdgcn_s_sleep(8);
        __syncthreads();
    }

    // ---- P7: copy-out; slice base = bptr (atomic read) + arrival-order
    // cursor claim (R10-validated) ----
    int lane4 = t & 3;
    int sgbase = lane & ~3;
    for (int k = (t >> 2); k < K_BUCKETS; k += FT / 4) {
        int lb = lbeg[k];
        int le = lcur[k];
        int cnt = le - lb;
        int d0 = 0;
        if (lane4 == 0 && cnt > 0)
            d0 = atomicAdd(&bptr[k], 0) + atomicAdd(&cursor[k], cnt);
        d0 = __shfl(d0, sgbase, 64);
        for (int i = lb + lane4; i < le; i += 4)
            entries[d0 + (i - lb)] = sbuf[i];
    }
}

// ---- nodesort + layer 1 fused (unchanged, R6-validated) ----
__global__ void __launch_bounds__(256) nodesort_pull1_kernel(
        const int* __restrict__ bptr, uint2* __restrict__ entries,
        int* __restrict__ row_ptr,
        const float* __restrict__ x, float* __restrict__ out) {
    __shared__ uint2 ebuf[CAP];          // 32 KB
    __shared__ int nh[BKT_NODES];
    __shared__ int nc[BKT_NODES];
    __shared__ int nstart[BKT_NODES + 1];
    int t = threadIdx.x, b = blockIdx.x;
    int beg = bptr[b], end = bptr[b + 1];
    int n = min(end - beg, CAP);
    if (t < BKT_NODES) nh[t] = 0;
    __syncthreads();
    uint2 rs[16];
    int cnt = 0;
    #pragma unroll
    for (int i = 0; i < 16; i++) {
        int k = t + i * 256;
        if (k < n) {
            uint2 r = entries[beg + k];
            rs[i] = r;
            atomicAdd(&nh[r.x >> 17], 1);
            cnt = i + 1;
        }
    }
    __syncthreads();
    if (t < BKT_NODES) {
        int v = nh[t];
        int pref = v;
        #pragma unroll
        for (int off = 1; off < BKT_NODES; off <<= 1) {
            int u = __shfl_up(pref, off, 64);
            if (t >= off) pref += u;
        }
        int excl = pref - v;
        nstart[t] = excl;
        nc[t] = excl;
        if (t == BKT_NODES - 1) nstart[BKT_NODES] = pref;
        int node = b * BKT_NODES + t;
        if (node < N_NODES) row_ptr[node] = beg + excl;
    }
    __syncthreads();
    #pragma unroll
    for (int i = 0; i < 16; i++) {
        if (i < cnt) {
            uint2 r = rs[i];
            int pos = atomicAdd(&nc[r.x >> 17], 1);
            ebuf[pos] = r;
            entries[beg + pos] = r;
        }
    }
    __syncthreads();
    int ln = t >> 2, q = t & 3;
    int node = b * BKT_NODES + ln;
    if (node >= N_NODES) return;
    int s = nstart[ln], e = nstart[ln + 1];
    float4 acc = make_float4(0.f, 0.f, 0.f, 0.f);
    int i = s;
    while (i + 8 <= e) {
        uint2 r0 = ebuf[i + 0], r1 = ebuf[i + 1], r2 = ebuf[i + 2], r3 = ebuf[i + 3];
        uint2 r4 = ebuf[i + 4], r5 = ebuf[i + 5], r6 = ebuf[i + 6], r7 = ebuf[i + 7];
        float4 y0 = *(const float4*)&x[(r0.x & 0x1FFFFu) * BATCH + q * 4];
        float4 y1 = *(const float4*)&x[(r1.x & 0x1FFFFu) * BATCH + q * 4];
        float4 y2 = *(const float4*)&x[(r2.x & 0x1FFFFu) * BATCH + q * 4];
        float4 y3 = *(const float4*)&x[(r3.x & 0x1FFFFu) * BATCH + q * 4];
        float4 y4 = *(const float4*)&x[(r4.x & 0x1FFFFu) * BATCH + q * 4];
        float4 y5 = *(const float4*)&x[(r5.x & 0x1FFFFu) * BATCH + q * 4];
        float4 y6 = *(const float4*)&x[(r6.x & 0x1FFFFu) * BATCH + q * 4];
        float4 y7 = *(const float4*)&x[(r7.x & 0x1FFFFu) * BATCH + q * 4];
        float w0 = __uint_as_float(r0.y), w1 = __uint_as_float(r1.y);
        float w2 = __uint_as_float(r2.y), w3 = __uint_as_float(r3.y);
        float w4 = __uint_as_float(r4.y), w5 = __uint_as_float(r5.y);
        float w6 = __uint_as_float(r6.y), w7 = __uint_as_float(r7.y);
        acc.x += w0 * y0.x; acc.y += w0 * y0.y; acc.z += w0 * y0.z; acc.w += w0 * y0.w;
        acc.x += w1 * y1.x; acc.y += w1 * y1.y; acc.z += w1 * y1.z; acc.w += w1 * y1.w;
        acc.x += w2 * y2.x; acc.y += w2 * y2.y; acc.z += w2 * y2.z; acc.w += w2 * y2.w;
        acc.x += w3 * y3.x; acc.y += w3 * y3.y; acc.z += w3 * y3.z; acc.w += w3 * y3.w;
        acc.x += w4 * y4.x; acc.y += w4 * y4.y; acc.z += w4 * y4.z; acc.w += w4 * y4.w;
        acc.x += w5 * y5.x; acc.y += w5 * y5.y; acc.z += w5 * y5.z; acc.w += w5 * y5.w;
        acc.x += w6 * y6.x; acc.y += w6 * y6.y; acc.z += w6 * y6.z; acc.w += w6 * y6.w;
        acc.x += w7 * y7.x; acc.y += w7 * y7.y; acc.z += w7 * y7.z; acc.w += w7 * y7.w;
        i += 8;
    }
    for (; i < e; i++) {
        uint2 r = ebuf[i];
        float4 yv = *(const float4*)&x[(r.x & 0x1FFFFu) * BATCH + q * 4];
        float wj = __uint_as_float(r.y);
        acc.x += wj * yv.x; acc.y += wj * yv.y;
        acc.z += wj * yv.z; acc.w += wj * yv.w;
    }
    *(float4*)&out[node * BATCH + q * 4] = acc;
}

// ---- layers 2-4: node-parallel CSR pull, float4 batch quads (4 threads/node).
// 3 separate dispatches (R12: in-kernel fusion condemned).
__global__ void __launch_bounds__(256) pull_kernel(const float* __restrict__ y,
                            const uint2* __restrict__ entries,
                            const int* __restrict__ row_ptr,
                            float* __restrict__ out) {
    int tid = blockIdx.x * blockDim.x + threadIdx.x;
    int node = tid >> 2;
    int q = tid & 3;
    if (node >= N_NODES) return;
    int beg = row_ptr[node];
    int end = row_ptr[node + 1];
    float4 acc = make_float4(0.f, 0.f, 0.f, 0.f);
    if (beg < end) {
        int lim = end - 1;
        uint2 r[8];
        #pragma unroll
        for (int j = 0; j < 8; j++) r[j] = entries[min(beg + j, lim)];
        int i = beg;
        while (i + 8 <= end) {
            float4 yv[8];
            #pragma unroll
            for (int j = 0; j < 8; j++)
                yv[j] = *(const float4*)&y[(r[j].x & 0x1FFFFu) * BATCH + q * 4];
            uint2 nx[8];
            #pragma unroll
            for (int j = 0; j < 8; j++)
                nx[j] = entries[min(i + 8 + j, lim)];
            #pragma unroll
            for (int j = 0; j < 8; j++) {
                float wj = __uint_as_float(r[j].y);
                acc.x += wj * yv[j].x;
                acc.y += wj * yv[j].y;
                acc.z += wj * yv[j].z;
                acc.w += wj * yv[j].w;
            }
            #pragma unroll
            for (int j = 0; j < 8; j++) r[j] = nx[j];
            i += 8;
        }
        if (i < end) {                       // masked epilogue, still batched
            float4 yv[8];
            #pragma unroll
            for (int j = 0; j < 8; j++)
                yv[j] = *(const float4*)&y[(r[j].x & 0x1FFFFu) * BATCH + q * 4];
            #pragma unroll
            for (int j = 0; j < 8; j++)
                if (i + j < end) {
                    float wj = __uint_as_float(r[j].y);
                    acc.x += wj * yv[j].x;
                    acc.y += wj * yv[j].y;
                    acc.z += wj * yv[j].z;
                    acc.w += wj * yv[j].w;
                }
        }
    }
    *(float4*)&out[node * BATCH + q * 4] = acc;
}

extern "C" void kernel_launch(void* const* d_in, const int* in_sizes, int n_in,
                              void* d_out, int out_size, void* d_ws, size_t ws_size,
                              hipStream_t stream) {
    const float* x   = (const float*)d_in[0];
    const float* w   = (const float*)d_in[1];
    const int*   row = (const int*)d_in[2];
    const int*   col = (const int*)d_in[3];
    float*       out = (float*)d_out;

    // ---- workspace carve-up (~32.4 MB; proven ws >= 33.2 MB) ----
    char* p = (char*)d_ws;
    uint2* entries = (uint2*)p;  p += (size_t)N_EDGES * sizeof(uint2);           // 25.6 MB
    float* buf     = (float*)p;  p += (size_t)N_NODES * BATCH * sizeof(float);   // 6.4 MB
    int* totals  = (int*)p;      p += 8192;
    int* bptr    = (int*)p;      p += 8192;
    int* cursor  = (int*)p;      p += 8192;
    int* row_ptr = (int*)p;      // 400 KB

    // ---- fused CSR build (init folded in; was zero + build) ----
    build_kernel<<<NB, FT, 0, stream>>>(row, col, w, totals, bptr, row_ptr,
                                        cursor, entries);

    // ---- nodesort + layer 1 fused (x -> buf), then layers 2-4 ----
    nodesort_pull1_kernel<<<K_BUCKETS, 256, 0, stream>>>(bptr, entries, row_ptr, x, buf);
    const int pgrid = (N_NODES * 4 + 255) / 256;   // 1563 blocks, 4 threads/node
    pull_kernel<<<pgrid, 256, 0, stream>>>(buf, entries, row_ptr, out);  // buf -> out
    pull_kernel<<<pgrid, 256, 0, stream>>>(out, entries, row_ptr, buf);  // out -> buf
    pull_kernel<<<pgrid, 256, 0, stream>>>(buf, entries, row_ptr, out);  // buf -> out
}